// Round 1
// baseline (800.128 us; speedup 1.0000x reference)
//
#include <hip/hip_runtime.h>
#include <math.h>

// Problem constants: B=512, T=256, F=D=1024, all fp32.
// Algebraic restructure:
//   q   = z @ Wq^T + bq                      [512,1024]   (GEMM BT, bias)
//   qk  = q @ Wk                             [512,1024]   (GEMM BN)     -- bk drops (softmax-invariant)
//   scores[b,t] = past[b,t,:] . qk[b,:]      streaming, online softmax
//   ctxf[b,f]   = sum_t w[b,t] past[b,t,f]   same streaming pass (past read ONCE)
//   out = ctxf @ Wv^T + bv                   [512,1024]   (GEMM BT, bias in add kernel)

#define MM 512
#define NN 1024
#define KK 1024

// ---------------- fp32 tiled GEMM, 64x64 tile, TK=16, 4x4 micro, split-K=2 ----
// C is [2][512][1024] partials (kz = blockIdx.z). BT=1: Bm is [N,K] (contract rows).
// SUMA=1: A is [2][512][1024] partials, summed on load. BIAS only applied at kz==0.
template<int BT, int SUMA, int BIAS>
__global__ __launch_bounds__(256) void gemm_f32(const float* __restrict__ A,
        const float* __restrict__ Bm, const float* __restrict__ bias,
        float* __restrict__ C)
{
    __shared__ float As[16][68];
    __shared__ float Bs[16][68];
    const int tid = threadIdx.x;
    const int tx = tid & 15, ty = tid >> 4;
    const int n0 = blockIdx.x * 64, m0 = blockIdx.y * 64, kz = blockIdx.z;
    const int kbeg = kz * 512;
    const int arow = tid >> 2, akq = tid & 3;   // 64 rows x 4 float4 along K

    float c[4][4] = {};

    for (int kt = 0; kt < 512; kt += 16) {
        const int k0 = kbeg + kt;
        // A tile -> As[k][m] (transposed scatter; 2-way bank alias = free)
        {
            const float* ap = A + (size_t)(m0 + arow) * KK + k0 + akq * 4;
            float4 a = *(const float4*)ap;
            if (SUMA) {
                float4 a2 = *(const float4*)(ap + MM * NN);
                a.x += a2.x; a.y += a2.y; a.z += a2.z; a.w += a2.w;
            }
            As[akq*4+0][arow] = a.x; As[akq*4+1][arow] = a.y;
            As[akq*4+2][arow] = a.z; As[akq*4+3][arow] = a.w;
        }
        if (BT) {  // Bm[N,K]: Bs[k][n] = Bm[n0+n][k0+k]
            const float* bp = Bm + (size_t)(n0 + arow) * KK + k0 + akq * 4;
            float4 b = *(const float4*)bp;
            Bs[akq*4+0][arow] = b.x; Bs[akq*4+1][arow] = b.y;
            Bs[akq*4+2][arow] = b.z; Bs[akq*4+3][arow] = b.w;
        } else {   // Bm[K,N]: direct row copy
            const int krow = tid >> 4, nq = tid & 15;
            float4 b = *(const float4*)(Bm + (size_t)(k0 + krow) * NN + n0 + nq * 4);
            *(float4*)&Bs[krow][nq * 4] = b;
        }
        __syncthreads();
        #pragma unroll
        for (int k = 0; k < 16; ++k) {
            float4 a4 = *(const float4*)&As[k][ty * 4];
            float4 b4 = *(const float4*)&Bs[k][tx * 4];
            float av[4] = {a4.x, a4.y, a4.z, a4.w};
            float bw[4] = {b4.x, b4.y, b4.z, b4.w};
            #pragma unroll
            for (int i = 0; i < 4; ++i)
                #pragma unroll
                for (int j = 0; j < 4; ++j)
                    c[i][j] = fmaf(av[i], bw[j], c[i][j]);
        }
        __syncthreads();
    }

    float* Cp = C + (size_t)kz * MM * NN;
    #pragma unroll
    for (int i = 0; i < 4; ++i) {
        const int m = m0 + ty * 4 + i;
        const int n = n0 + tx * 4;
        float4 o = make_float4(c[i][0], c[i][1], c[i][2], c[i][3]);
        if (BIAS && kz == 0) {
            o.x += bias[n]; o.y += bias[n+1]; o.z += bias[n+2]; o.w += bias[n+3];
        }
        *(float4*)&Cp[(size_t)m * NN + n] = o;
    }
}

// ---------------- streaming attention: one block per b, online softmax -------
// Each thread owns 4 f-columns; past[b,t,:] rows read once (coalesced 4KB/row).
__global__ __launch_bounds__(256) void attn_stream(const float* __restrict__ past,
        const float* __restrict__ qk2, float* __restrict__ ctx)
{
    const int b = blockIdx.x;
    const int e = threadIdx.x;            // 0..255
    const int lane = e & 63, w = e >> 6;  // 4 waves
    __shared__ float red[2][4][8];

    const float* qp = qk2 + (size_t)b * 1024 + e * 4;
    float4 q4 = *(const float4*)qp;
    {   // sum split-K partials of qk
        float4 q4b = *(const float4*)(qp + MM * NN);
        q4.x += q4b.x; q4.y += q4b.y; q4.z += q4b.z; q4.w += q4b.w;
    }

    float4 acc = make_float4(0.f, 0.f, 0.f, 0.f);
    float m = -INFINITY, l = 0.f;
    const float* base = past + (size_t)b * 256 * 1024 + e * 4;

    for (int t0 = 0; t0 < 256; t0 += 8) {
        const int buf = (t0 >> 3) & 1;
        float4 r[8];
        float p[8];
        #pragma unroll
        for (int j = 0; j < 8; ++j)
            r[j] = *(const float4*)(base + (size_t)(t0 + j) * 1024);
        #pragma unroll
        for (int j = 0; j < 8; ++j)
            p[j] = q4.x*r[j].x + q4.y*r[j].y + q4.z*r[j].z + q4.w*r[j].w;
        // wave-level butterfly reduce (all lanes end with wave sum)
        #pragma unroll
        for (int j = 0; j < 8; ++j) {
            #pragma unroll
            for (int off = 1; off < 64; off <<= 1)
                p[j] += __shfl_xor(p[j], off, 64);
        }
        if (lane == 0) {
            #pragma unroll
            for (int j = 0; j < 8; ++j) red[buf][w][j] = p[j];
        }
        __syncthreads();
        float s[8];
        #pragma unroll
        for (int j = 0; j < 8; ++j)
            s[j] = red[buf][0][j] + red[buf][1][j] + red[buf][2][j] + red[buf][3][j];

        float cmax = s[0];
        #pragma unroll
        for (int j = 1; j < 8; ++j) cmax = fmaxf(cmax, s[j]);
        const float mn = fmaxf(m, cmax);
        const float alpha = __expf(m - mn);   // first iter: exp(-inf)=0
        float pe[8], sum = 0.f;
        #pragma unroll
        for (int j = 0; j < 8; ++j) { pe[j] = __expf(s[j] - mn); sum += pe[j]; }
        l = l * alpha + sum;
        acc.x *= alpha; acc.y *= alpha; acc.z *= alpha; acc.w *= alpha;
        #pragma unroll
        for (int j = 0; j < 8; ++j) {
            acc.x = fmaf(pe[j], r[j].x, acc.x);
            acc.y = fmaf(pe[j], r[j].y, acc.y);
            acc.z = fmaf(pe[j], r[j].z, acc.z);
            acc.w = fmaf(pe[j], r[j].w, acc.w);
        }
        m = mn;
    }
    const float inv = 1.0f / l;
    float4 o = make_float4(acc.x * inv, acc.y * inv, acc.z * inv, acc.w * inv);
    *(float4*)(ctx + (size_t)b * 1024 + e * 4) = o;
}

// ---------------- final: out = o2[0] + o2[1] + bv ----------------------------
__global__ __launch_bounds__(256) void add_bias_out(const float* __restrict__ o2,
        const float* __restrict__ bv, float* __restrict__ out)
{
    const int i = (blockIdx.x * 256 + threadIdx.x) * 4;   // over 512*1024
    float4 a = *(const float4*)(o2 + i);
    float4 b = *(const float4*)(o2 + MM * NN + i);
    const int n = i & 1023;
    float4 bb = *(const float4*)(bv + n);
    float4 r = make_float4(a.x + b.x + bb.x, a.y + b.y + bb.y,
                           a.z + b.z + bb.z, a.w + b.w + bb.w);
    *(float4*)(out + i) = r;
}

extern "C" void kernel_launch(void* const* d_in, const int* in_sizes, int n_in,
                              void* d_out, int out_size, void* d_ws, size_t ws_size,
                              hipStream_t stream) {
    const float* z    = (const float*)d_in[0];
    const float* past = (const float*)d_in[1];
    const float* Wq   = (const float*)d_in[2];
    const float* Wk   = (const float*)d_in[3];
    const float* Wv   = (const float*)d_in[4];
    const float* bq   = (const float*)d_in[5];
    // d_in[6] = bk: constant over t in scores -> softmax-invariant, unused.
    const float* bv   = (const float*)d_in[7];
    float* out = (float*)d_out;

    // workspace layout (floats): q2[2*512*1024] | qk2[2*512*1024] | ctx[512*1024]
    float* q2  = (float*)d_ws;
    float* qk2 = q2 + 2 * MM * NN;
    float* ctx = qk2 + 2 * MM * NN;
    float* o2  = q2;   // reuse q2 region for output partials (q dead after GEMM2)

    dim3 g(NN / 64, MM / 64, 2), blk(256);
    gemm_f32<1, 0, 1><<<g, blk, 0, stream>>>(z,   Wq, bq,      q2);   // q  = z @ Wq^T + bq
    gemm_f32<0, 1, 0><<<g, blk, 0, stream>>>(q2,  Wk, nullptr, qk2);  // qk = q @ Wk
    attn_stream<<<dim3(512), blk, 0, stream>>>(past, qk2, ctx);       // softmax + weighted sum
    gemm_f32<1, 0, 0><<<g, blk, 0, stream>>>(ctx, Wv, nullptr, o2);   // ctxf @ Wv^T
    add_bias_out<<<dim3(512), blk, 0, stream>>>(o2, bv, out);         // + bv
}